// Round 5
// baseline (120.420 us; speedup 1.0000x reference)
//
#include <hip/hip_runtime.h>

typedef _Float16 f16;
typedef f16 f16x4 __attribute__((ext_vector_type(4)));
typedef f16 f16x8 __attribute__((ext_vector_type(8)));
typedef float f32x16 __attribute__((ext_vector_type(16)));

#define NB 8
#define NC 128
#define NZ 4
#define NS 8
#define NT 1024
#define NH 64

#define WQ_N (NC*NZ*NS*NH)   // 262144
#define WK_N (NB*NZ*NT*NH)   // 2097152

#define OUT_CTX  (NB*NC*NZ*NS*NT)          // 33554432
#define OUT_ATTN (OUT_CTX + NB*NC*NZ*NH)   // 33816576

__device__ __forceinline__ float fast_tanh(float x) {
    // tanh(x) = 1 - 2/(exp(2x)+1); exact at saturation
    float e = __expf(2.0f * x);
    return 1.0f - 2.0f * __builtin_amdgcn_rcpf(e + 1.0f);
}

// ---------------- prep: tanh + fp16 convert (+ K transpose) ----------------
__global__ __launch_bounds__(256) void prep_kernel(
    const float* __restrict__ WQ, const float* __restrict__ WK, const float* __restrict__ K,
    f16* __restrict__ wqh, f16* __restrict__ wkh, f16* __restrict__ ktT)
{
    __shared__ f16 ldsT[64*64];
    const int tid = threadIdx.x;
    const int blk = blockIdx.x;
    if (blk < 512) {
        const int bz = blk >> 4;
        const int t0 = (blk & 15) << 6;   // 64-row t tile
        #pragma unroll
        for (int it = 0; it < 4; ++it) {
            int idx = it*256 + tid;
            int tl  = idx >> 4;      // 0..63 (t within tile)
            int seg = idx & 15;      // float4 segment of the 64-h row
            int gi  = (bz*NT + t0 + tl)*NH + seg*4;
            float4 wk4 = *(const float4*)(WK + gi);
            float4 k4  = *(const float4*)(K  + gi);
            f16x4 wv;
            wv[0] = (f16)fast_tanh(wk4.x);
            wv[1] = (f16)fast_tanh(wk4.y);
            wv[2] = (f16)fast_tanh(wk4.z);
            wv[3] = (f16)fast_tanh(wk4.w);
            *(f16x4*)(wkh + gi) = wv;
            ldsT[(seg*4+0)*64 + tl] = (f16)fast_tanh(k4.x);
            ldsT[(seg*4+1)*64 + tl] = (f16)fast_tanh(k4.y);
            ldsT[(seg*4+2)*64 + tl] = (f16)fast_tanh(k4.z);
            ldsT[(seg*4+3)*64 + tl] = (f16)fast_tanh(k4.w);
        }
        __syncthreads();
        #pragma unroll
        for (int it = 0; it < 4; ++it) {
            int idx = it*256 + tid;
            int h  = idx >> 4;
            int ts = idx & 15;
            f16x4 v = *(const f16x4*)&ldsT[h*64 + ts*4];
            *(f16x4*)(ktT + (bz*NH + h)*NT + t0 + ts*4) = v;
        }
    } else {
        const int ib = blk - 512;   // 16 blocks cover 262144 WQ elems
        #pragma unroll
        for (int it = 0; it < 16; ++it) {
            int gi = ib*16384 + it*1024 + tid*4;
            float4 q = *(const float4*)(WQ + gi);
            f16x4 w;
            w[0] = (f16)q.x; w[1] = (f16)q.y; w[2] = (f16)q.z; w[3] = (f16)q.w;
            *(f16x4*)(wqh + gi) = w;
        }
    }
}

// -------- fused: QK^T + scores-write + softmax + attn-write + PV ----------
// Hold variant with bf16-packed exp strip: exp(scores) for the whole 32x1024
// row strip is kept register-resident as bf16 pairs (64 VGPRs), so no
// recompute and no scores re-read, at 3 blocks/CU.
__global__ __launch_bounds__(256, 3) void fused_kernel(
    const f16* __restrict__ wqh, const f16* __restrict__ wkh, const f16* __restrict__ ktT,
    float* __restrict__ scores, float* __restrict__ attn, float* __restrict__ ctxout)
{
    __shared__ float rsL[4][32];
    __shared__ float invL[32];
    __shared__ f16   attnB[4][1024];        // per-wave 32m x 32t, blocked+XOR layout
    __shared__ float ctxW[4][32][64];       // per-wave partial context

    const int tid  = threadIdx.x;
    const int wave = tid >> 6;
    const int lane = tid & 63;
    const int l31  = lane & 31;
    const int g    = lane >> 5;
    const int bid  = blockIdx.x;
    const int bz = bid & 31, mt = bid >> 5;
    const int b = bz >> 2, z = bz & 3;
    const int m0 = mt * 32;

    // ---- A fragments (WQ rows m0..m0+31), k = h = 16*st + 8*g + e ----
    const int mgA = m0 + l31;
    const f16* ap = wqh + (((mgA >> 3)*NZ + z)*NS + (mgA & 7))*NH + g*8;
    f16x8 afr[4];
    #pragma unroll
    for (int st = 0; st < 4; ++st) afr[st] = *(const f16x8*)(ap + st*16);

    const int base2 = ((b*NC + mt*4)*NZ + z)*NS*NT;

    // ---- phase 1: QK^T per tile -> store scores, hold exp as packed bf16 ----
    unsigned pe[8][8];           // [tt][r/2] : two bf16 exp values per reg
    float p[16];
    #pragma unroll
    for (int r = 0; r < 16; ++r) p[r] = 0.f;

    #pragma unroll
    for (int tt = 0; tt < 8; ++tt) {
        const int t0 = (tt*4 + wave) * 32;
        const f16* bp = wkh + (bz*NT + t0 + l31)*NH + g*8;
        f32x16 acc;
        #pragma unroll
        for (int r = 0; r < 16; ++r) acc[r] = 0.f;
        #pragma unroll
        for (int st = 0; st < 4; ++st) {
            f16x8 bfr = *(const f16x8*)(bp + st*16);
            acc = __builtin_amdgcn_mfma_f32_32x32x16_f16(afr[st], bfr, acc, 0, 0, 0);
        }
        const int tcol = t0 + l31;
        #pragma unroll
        for (int r = 0; r < 16; ++r) {
            float v = acc[r];
            scores[base2 + (r >> 2)*32768 + ((r & 3) + 4*g)*1024 + tcol] = v;
            float e = __expf(v);
            p[r] += e;
            unsigned ube = __float_as_uint(e);
            ube = (ube + 0x7FFFu + ((ube >> 16) & 1u)) >> 16;   // round-to-nearest bf16
            if (r & 1) pe[tt][r >> 1] |= ube << 16;
            else       pe[tt][r >> 1]  = ube;
        }
    }

    // reduce over the 32 t-columns (stays within each 32-lane half)
    #pragma unroll
    for (int d = 1; d < 32; d <<= 1)
        #pragma unroll
        for (int r = 0; r < 16; ++r) p[r] += __shfl_xor(p[r], d, 64);

    if (l31 == 0) {
        #pragma unroll
        for (int r = 0; r < 16; ++r) rsL[wave][(r & 3) + 8*(r >> 2) + 4*g] = p[r];
    }
    __syncthreads();
    if (tid < 32) invL[tid] = 1.0f / (rsL[0][tid] + rsL[1][tid] + rsL[2][tid] + rsL[3][tid]);
    __syncthreads();

    // ---- phase 2: attn = exp*inv (write), fp16 -> LDS, PV MFMA ----
    f32x16 cacc[2];
    #pragma unroll
    for (int nt = 0; nt < 2; ++nt)
        #pragma unroll
        for (int r = 0; r < 16; ++r) cacc[nt][r] = 0.f;

    #pragma unroll
    for (int tt = 0; tt < 8; ++tt) {
        const int t0 = (tt*4 + wave) * 32;
        const int tcol = t0 + l31;
        #pragma unroll
        for (int r = 0; r < 16; ++r) {
            unsigned ube = (r & 1) ? (pe[tt][r >> 1] >> 16) : (pe[tt][r >> 1] & 0xFFFFu);
            float e = __uint_as_float(ube << 16);
            int ml = (r & 3) + 8*(r >> 2) + 4*g;
            float a = e * invL[ml];
            attn[base2 + (r >> 2)*32768 + ((r & 3) + 4*g)*1024 + tcol] = a;
            int tb = l31 >> 3;
            int ai = ((tb*32 + ml)*8 + (l31 & 7)) ^ (tb << 3);
            attnB[wave][ai] = (f16)a;
        }
        // PV: A = attn tile (k = t), B = Kt (from ktT, contiguous 16B)
        #pragma unroll
        for (int s2 = 0; s2 < 2; ++s2) {
            int tb = 2*s2 + g;
            int ai = ((tb*32 + l31)*8) ^ (tb << 3);
            f16x8 pa = *(const f16x8*)&attnB[wave][ai];
            #pragma unroll
            for (int nt = 0; nt < 2; ++nt) {
                const f16* bp2 = ktT + (bz*NH + nt*32 + l31)*NT + t0 + s2*16 + g*8;
                f16x8 bf = *(const f16x8*)bp2;
                cacc[nt] = __builtin_amdgcn_mfma_f32_32x32x16_f16(pa, bf, cacc[nt], 0, 0, 0);
            }
        }
    }

    // ---- per-wave partial context to LDS ----
    #pragma unroll
    for (int nt = 0; nt < 2; ++nt) {
        #pragma unroll
        for (int r = 0; r < 16; ++r) {
            int ml = (r & 3) + 8*(r >> 2) + 4*g;
            ctxW[wave][ml][nt*32 + l31] = cacc[nt][r];
        }
    }
    __syncthreads();

    // ---- context = mean over s (and sum over waves' t-partitions) ----
    {
        int cl = tid >> 6;      // 0..3 local c
        int h  = tid & 63;
        float sum = 0.f;
        #pragma unroll
        for (int w = 0; w < 4; ++w)
            #pragma unroll
            for (int q = 0; q < 8; ++q)
                sum += ctxW[w][cl*8 + q][h];
        ctxout[((b*NC + (m0 >> 3) + cl)*NZ + z)*NH + h] = sum * 0.125f;
    }
}

extern "C" void kernel_launch(void* const* d_in, const int* in_sizes, int n_in,
                              void* d_out, int out_size, void* d_ws, size_t ws_size,
                              hipStream_t stream)
{
    const float* WQ = (const float*)d_in[0];
    const float* WK = (const float*)d_in[1];
    const float* K  = (const float*)d_in[2];

    char* ws = (char*)d_ws;
    f16* wqh = (f16*)(ws);
    f16* wkh = (f16*)(ws + (size_t)WQ_N*2);
    f16* ktT = (f16*)(ws + (size_t)WQ_N*2 + (size_t)WK_N*2);

    float* out    = (float*)d_out;
    float* scores = out;
    float* ctxout = out + OUT_CTX;
    float* attn   = out + OUT_ATTN;

    hipLaunchKernelGGL(prep_kernel, dim3(528), dim3(256), 0, stream,
                       WQ, WK, K, wqh, wkh, ktT);
    hipLaunchKernelGGL(fused_kernel, dim3(1024), dim3(256), 0, stream,
                       wqh, wkh, ktT, scores, attn, ctxout);
}

// Round 6
// 71.075 us; speedup vs baseline: 1.6943x; 1.6943x over previous
//
#include <hip/hip_runtime.h>

typedef _Float16 f16;
typedef f16 f16x4 __attribute__((ext_vector_type(4)));
typedef f16 f16x8 __attribute__((ext_vector_type(8)));
typedef float f32x16 __attribute__((ext_vector_type(16)));

#define NB 8
#define NC 128
#define NZ 4
#define NS 8
#define NT 1024
#define NH 64

#define WQ_N (NC*NZ*NS*NH)   // 262144
#define WK_N (NB*NZ*NT*NH)   // 2097152

#define OUT_CTX  (NB*NC*NZ*NS*NT)          // 33554432
#define OUT_ATTN (OUT_CTX + NB*NC*NZ*NH)   // 33816576

__device__ __forceinline__ float fast_tanh(float x) {
    // tanh(x) = 1 - 2/(exp(2x)+1); exact at saturation
    float e = __expf(2.0f * x);
    return 1.0f - 2.0f * __builtin_amdgcn_rcpf(e + 1.0f);
}

// ---------------- prep: tanh + fp16 convert (+ K transpose) ----------------
__global__ __launch_bounds__(256) void prep_kernel(
    const float* __restrict__ WQ, const float* __restrict__ WK, const float* __restrict__ K,
    f16* __restrict__ wqh, f16* __restrict__ wkh, f16* __restrict__ ktT)
{
    __shared__ f16 ldsT[64*64];
    const int tid = threadIdx.x;
    const int blk = blockIdx.x;
    if (blk < 512) {
        const int bz = blk >> 4;
        const int t0 = (blk & 15) << 6;   // 64-row t tile
        #pragma unroll
        for (int it = 0; it < 4; ++it) {
            int idx = it*256 + tid;
            int tl  = idx >> 4;      // 0..63 (t within tile)
            int seg = idx & 15;      // float4 segment of the 64-h row
            int gi  = (bz*NT + t0 + tl)*NH + seg*4;
            float4 wk4 = *(const float4*)(WK + gi);
            float4 k4  = *(const float4*)(K  + gi);
            f16x4 wv;
            wv[0] = (f16)fast_tanh(wk4.x);
            wv[1] = (f16)fast_tanh(wk4.y);
            wv[2] = (f16)fast_tanh(wk4.z);
            wv[3] = (f16)fast_tanh(wk4.w);
            *(f16x4*)(wkh + gi) = wv;
            ldsT[(seg*4+0)*64 + tl] = (f16)fast_tanh(k4.x);
            ldsT[(seg*4+1)*64 + tl] = (f16)fast_tanh(k4.y);
            ldsT[(seg*4+2)*64 + tl] = (f16)fast_tanh(k4.z);
            ldsT[(seg*4+3)*64 + tl] = (f16)fast_tanh(k4.w);
        }
        __syncthreads();
        #pragma unroll
        for (int it = 0; it < 4; ++it) {
            int idx = it*256 + tid;
            int h  = idx >> 4;
            int ts = idx & 15;
            f16x4 v = *(const f16x4*)&ldsT[h*64 + ts*4];
            *(f16x4*)(ktT + (bz*NH + h)*NT + t0 + ts*4) = v;
        }
    } else {
        const int ib = blk - 512;   // 16 blocks cover 262144 WQ elems
        #pragma unroll
        for (int it = 0; it < 16; ++it) {
            int gi = ib*16384 + it*1024 + tid*4;
            float4 q = *(const float4*)(WQ + gi);
            f16x4 w;
            w[0] = (f16)q.x; w[1] = (f16)q.y; w[2] = (f16)q.z; w[3] = (f16)q.w;
            *(f16x4*)(wqh + gi) = w;
        }
    }
}

// -------- fused: QK^T + scores-write + softmax + attn-write + PV ----------
// R2 structure: full 32x1024 f32 score strip register-resident (128 VGPR),
// 2 blocks/CU. Measured best (71.9 us total); R4 (recompute+NT, 3/CU) and
// R5 (bf16-pack, 3/CU -> spills) both regressed.
__global__ __launch_bounds__(256, 2) void fused_kernel(
    const f16* __restrict__ wqh, const f16* __restrict__ wkh, const f16* __restrict__ ktT,
    float* __restrict__ scores, float* __restrict__ attn, float* __restrict__ ctxout)
{
    __shared__ float rsL[4][32];
    __shared__ float invL[32];
    __shared__ f16   attnB[4][1024];        // per-wave 32m x 32t, blocked+XOR layout
    __shared__ float ctxW[4][32][64];       // per-wave partial context

    const int tid  = threadIdx.x;
    const int wave = tid >> 6;
    const int lane = tid & 63;
    const int l31  = lane & 31;
    const int g    = lane >> 5;
    const int bid  = blockIdx.x;
    const int bz = bid & 31, mt = bid >> 5;
    const int b = bz >> 2, z = bz & 3;
    const int m0 = mt * 32;

    // ---- A fragments (WQ rows m0..m0+31), k = h = 16*st + 8*g + e ----
    const int mgA = m0 + l31;
    const f16* ap = wqh + (((mgA >> 3)*NZ + z)*NS + (mgA & 7))*NH + g*8;
    f16x8 afr[4];
    #pragma unroll
    for (int st = 0; st < 4; ++st) afr[st] = *(const f16x8*)(ap + st*16);

    // ---- QK^T: full 32-row strip register-resident ----
    f32x16 acc[8];
    #pragma unroll
    for (int tt = 0; tt < 8; ++tt)
        #pragma unroll
        for (int r = 0; r < 16; ++r) acc[tt][r] = 0.f;

    #pragma unroll
    for (int tt = 0; tt < 8; ++tt) {
        const int t0 = (tt*4 + wave) * 32;
        const f16* bp = wkh + (bz*NT + t0 + l31)*NH + g*8;
        #pragma unroll
        for (int st = 0; st < 4; ++st) {
            f16x8 bfr = *(const f16x8*)(bp + st*16);
            acc[tt] = __builtin_amdgcn_mfma_f32_32x32x16_f16(afr[st], bfr, acc[tt], 0, 0, 0);
        }
    }

    // ---- write scores, acc <- exp(acc), accumulate rowsum ----
    const int base2 = ((b*NC + mt*4)*NZ + z)*NS*NT;
    float p[16];
    #pragma unroll
    for (int r = 0; r < 16; ++r) p[r] = 0.f;

    #pragma unroll
    for (int tt = 0; tt < 8; ++tt) {
        const int tcol = (tt*4 + wave)*32 + l31;
        #pragma unroll
        for (int r = 0; r < 16; ++r) {
            int off = base2 + (r >> 2)*32768 + ((r & 3) + 4*g)*1024 + tcol;
            float v = acc[tt][r];
            scores[off] = v;
            float e = __expf(v);
            acc[tt][r] = e;
            p[r] += e;
        }
    }

    // reduce over the 32 t-columns (stays within each 32-lane half)
    #pragma unroll
    for (int d = 1; d < 32; d <<= 1)
        #pragma unroll
        for (int r = 0; r < 16; ++r) p[r] += __shfl_xor(p[r], d, 64);

    if (l31 == 0) {
        #pragma unroll
        for (int r = 0; r < 16; ++r) rsL[wave][(r & 3) + 8*(r >> 2) + 4*g] = p[r];
    }
    __syncthreads();
    if (tid < 32) invL[tid] = 1.0f / (rsL[0][tid] + rsL[1][tid] + rsL[2][tid] + rsL[3][tid]);
    __syncthreads();

    // ---- attn = exp*inv (write), fp16 -> LDS, PV MFMA ----
    f32x16 cacc[2];
    #pragma unroll
    for (int nt = 0; nt < 2; ++nt)
        #pragma unroll
        for (int r = 0; r < 16; ++r) cacc[nt][r] = 0.f;

    #pragma unroll
    for (int tt = 0; tt < 8; ++tt) {
        const int t0 = (tt*4 + wave) * 32;
        const int tcol = t0 + l31;
        #pragma unroll
        for (int r = 0; r < 16; ++r) {
            int ml = (r & 3) + 8*(r >> 2) + 4*g;
            float a = acc[tt][r] * invL[ml];
            int off = base2 + (r >> 2)*32768 + ((r & 3) + 4*g)*1024 + tcol;
            attn[off] = a;
            int tb = l31 >> 3;
            int ai = ((tb*32 + ml)*8 + (l31 & 7)) ^ (tb << 3);
            attnB[wave][ai] = (f16)a;
        }
        // PV: A = attn tile (k = t), B = Kt (from ktT, contiguous 16B)
        #pragma unroll
        for (int s2 = 0; s2 < 2; ++s2) {
            int tb = 2*s2 + g;
            int ai = ((tb*32 + l31)*8) ^ (tb << 3);
            f16x8 pa = *(const f16x8*)&attnB[wave][ai];
            #pragma unroll
            for (int nt = 0; nt < 2; ++nt) {
                const f16* bp2 = ktT + (bz*NH + nt*32 + l31)*NT + t0 + s2*16 + g*8;
                f16x8 bf = *(const f16x8*)bp2;
                cacc[nt] = __builtin_amdgcn_mfma_f32_32x32x16_f16(pa, bf, cacc[nt], 0, 0, 0);
            }
        }
    }

    // ---- per-wave partial context to LDS ----
    #pragma unroll
    for (int nt = 0; nt < 2; ++nt) {
        #pragma unroll
        for (int r = 0; r < 16; ++r) {
            int ml = (r & 3) + 8*(r >> 2) + 4*g;
            ctxW[wave][ml][nt*32 + l31] = cacc[nt][r];
        }
    }
    __syncthreads();

    // ---- context = mean over s (and sum over waves' t-partitions) ----
    {
        int cl = tid >> 6;      // 0..3 local c
        int h  = tid & 63;
        float sum = 0.f;
        #pragma unroll
        for (int w = 0; w < 4; ++w)
            #pragma unroll
            for (int q = 0; q < 8; ++q)
                sum += ctxW[w][cl*8 + q][h];
        ctxout[((b*NC + (m0 >> 3) + cl)*NZ + z)*NH + h] = sum * 0.125f;
    }
}

extern "C" void kernel_launch(void* const* d_in, const int* in_sizes, int n_in,
                              void* d_out, int out_size, void* d_ws, size_t ws_size,
                              hipStream_t stream)
{
    const float* WQ = (const float*)d_in[0];
    const float* WK = (const float*)d_in[1];
    const float* K  = (const float*)d_in[2];

    char* ws = (char*)d_ws;
    f16* wqh = (f16*)(ws);
    f16* wkh = (f16*)(ws + (size_t)WQ_N*2);
    f16* ktT = (f16*)(ws + (size_t)WQ_N*2 + (size_t)WK_N*2);

    float* out    = (float*)d_out;
    float* scores = out;
    float* ctxout = out + OUT_CTX;
    float* attn   = out + OUT_ATTN;

    hipLaunchKernelGGL(prep_kernel, dim3(528), dim3(256), 0, stream,
                       WQ, WK, K, wqh, wkh, ktT);
    hipLaunchKernelGGL(fused_kernel, dim3(1024), dim3(256), 0, stream,
                       wqh, wkh, ktT, scores, attn, ctxout);
}